// Round 4
// baseline (2082.774 us; speedup 1.0000x reference)
//
#include <hip/hip_runtime.h>

#define NN 100000      // nodes
#define NE 1000000     // edges
#define NG 1024        // graphs
#define NSG 128        // subgraphs
#define EF 32          // edge feature dim
#define HH 64          // hidden
#define NOUT 32        // output classes
#define NL 3           // layers

// wave-uniform broadcast of lane l's value (v_readlane -> SGPR)
__device__ __forceinline__ float bcastf(float v, int l) {
    return __int_as_float(__builtin_amdgcn_readlane(__float_as_int(v), l));
}

// wave-internal LDS producer->consumer handoff (no cross-wave sharing)
__device__ __forceinline__ void wave_lds_sync() {
    __builtin_amdgcn_wave_barrier();
    asm volatile("s_waitcnt lgkmcnt(0)" ::: "memory");
    __builtin_amdgcn_wave_barrier();
}

// ---------------------------------------------------------------------------
__global__ void cnt_kernel(const int* __restrict__ batch, float* __restrict__ cnt) {
    int i = blockIdx.x * blockDim.x + threadIdx.x;
    if (i < NN) atomicAdd(&cnt[batch[i]], 1.0f);
}

__global__ void norm_kernel(const int* __restrict__ sgb, const float* __restrict__ w,
                            float* __restrict__ norm) {
    int i = blockIdx.x * blockDim.x + threadIdx.x;
    if (i < NG) atomicAdd(&norm[sgb[i]], w[i]);
}

// ---------------------------------------------------------------------------
// Edge pass, lane-owns-edge; weights staged in LDS (ds_read_b128 broadcast --
// the scalar path thrashes K$ at 24KB/tile, LDS does not). 8-edge LDS chunk
// transpose feeds the feature-parallel gather+relu+scatter phase.
__global__ __launch_bounds__(256, 4) void edge_fused(
    const float* __restrict__ hin,       // [NN,64]
    const float* __restrict__ eattr,     // [NE,32]
    const int*   __restrict__ eidx,      // [2,NE]
    const float* __restrict__ w1,        // [32,64]
    const float* __restrict__ b1,        // [64]
    const float* __restrict__ w2,        // [64,64]
    const float* __restrict__ b2,        // [64]
    float*       __restrict__ agg)       // [NN,64]
{
    __shared__ float wlds[EF * HH + HH * HH];   // 6144 floats = 24.0 KB
    __shared__ float tb[4][8 * 68];             // 8.5 KB; stride 68: 16B-aligned rows
    // cooperative weight staging (all waves, before any early-out)
    {
        const float4* s1 = (const float4*)w1;   // 512 float4
        const float4* s2 = (const float4*)w2;   // 1024 float4
        float4* d = (float4*)wlds;
        for (int i = threadIdx.x; i < 512; i += 256) d[i] = s1[i];
        for (int i = threadIdx.x; i < 1024; i += 256) d[512 + i] = s2[i];
    }
    __syncthreads();

    const int lane = threadIdx.x & 63;
    const int wv   = threadIdx.x >> 6;
    float* T = tb[wv];
    const float* w1s = wlds;               // [32][64]
    const float* w2s = wlds + EF * HH;     // [64][64]

    const int tile = blockIdx.x * 4 + wv;  // 15625 tiles of 64 edges
    const int base = tile * 64;
    if (base >= NE) return;
    const int e = base + lane;             // NE % 64 == 0, no tail

    // per-lane edge attributes
    float a[EF];
    const float4* ap = (const float4*)(eattr + (size_t)e * EF);
    #pragma unroll
    for (int c = 0; c < 8; ++c) {
        const float4 v4 = ap[c];
        a[4*c] = v4.x; a[4*c+1] = v4.y; a[4*c+2] = v4.z; a[4*c+3] = v4.w;
    }

    float emb[HH];
    #pragma unroll
    for (int k = 0; k < HH; ++k) emb[k] = b2[k];

    // j-blocked MLP; weights via ds_read_b128 (wave-uniform broadcast)
    #pragma unroll 1
    for (int jb = 0; jb < 8; ++jb) {
        const int j0 = jb * 8;
        float t[8];
        #pragma unroll
        for (int q = 0; q < 8; ++q) t[q] = b1[j0 + q];
        #pragma unroll
        for (int i = 0; i < EF; ++i) {
            const float ai = a[i];
            const float4 wA = *(const float4*)&w1s[i * HH + j0];
            const float4 wB = *(const float4*)&w1s[i * HH + j0 + 4];
            t[0] = fmaf(ai, wA.x, t[0]); t[1] = fmaf(ai, wA.y, t[1]);
            t[2] = fmaf(ai, wA.z, t[2]); t[3] = fmaf(ai, wA.w, t[3]);
            t[4] = fmaf(ai, wB.x, t[4]); t[5] = fmaf(ai, wB.y, t[5]);
            t[6] = fmaf(ai, wB.z, t[6]); t[7] = fmaf(ai, wB.w, t[7]);
        }
        #pragma unroll
        for (int q = 0; q < 8; ++q) {
            const float tq = fmaxf(t[q], 0.0f);
            const float* wr = w2s + (j0 + q) * HH;
            #pragma unroll
            for (int kc = 0; kc < 16; ++kc) {
                const float4 wv4 = *(const float4*)&wr[kc * 4];
                emb[kc*4+0] = fmaf(tq, wv4.x, emb[kc*4+0]);
                emb[kc*4+1] = fmaf(tq, wv4.y, emb[kc*4+1]);
                emb[kc*4+2] = fmaf(tq, wv4.z, emb[kc*4+2]);
                emb[kc*4+3] = fmaf(tq, wv4.w, emb[kc*4+3]);
            }
        }
    }

    // phase 2: 8-edge chunks through LDS, feature-parallel scatter
    #pragma unroll 1
    for (int cb = 0; cb < 8; ++cb) {
        const int r = lane & 7;
        if ((lane >> 3) == cb) {
            #pragma unroll
            for (int kc = 0; kc < 16; ++kc)
                *(float4*)&T[r * 68 + kc * 4] =
                    float4{emb[kc*4], emb[kc*4+1], emb[kc*4+2], emb[kc*4+3]};
        }
        wave_lds_sync();
        #pragma unroll
        for (int e2 = 0; e2 < 8; ++e2) {
            const int ge  = base + cb * 8 + e2;
            const int src = eidx[ge];            // wave-uniform -> s_load (tiny)
            const int dst = eidx[NE + ge];
            const float emv = T[e2 * 68 + lane];
            const float msg = fmaxf(hin[(size_t)src * HH + lane] + emv, 0.0f);
            atomicAdd(&agg[(size_t)dst * HH + lane], msg);
        }
        wave_lds_sync();
    }
}

// ---------------------------------------------------------------------------
// Node pass, lane-owns-node; LDS-staged weights; 8-node chunk transpose for
// coalesced in-place store + BN sum/sumsq.
__global__ __launch_bounds__(256, 3) void node_fused(
    const float* __restrict__ hin,
    float*       agg,                    // in: agg, out: v (same rows only)
    const float* __restrict__ w1, const float* __restrict__ b1,
    const float* __restrict__ w2, const float* __restrict__ b2,
    const float* __restrict__ epsp,
    float*       __restrict__ stats)     // [0:64] sum, [64:128] sumsq
{
    __shared__ float wlds[2 * HH * HH];         // 8192 floats = 32 KB
    __shared__ float tb[4][8 * 68];             // 8.5 KB
    {
        const float4* s1 = (const float4*)w1;   // 1024 float4
        const float4* s2 = (const float4*)w2;   // 1024 float4
        float4* d = (float4*)wlds;
        for (int i = threadIdx.x; i < 1024; i += 256) d[i] = s1[i];
        for (int i = threadIdx.x; i < 1024; i += 256) d[1024 + i] = s2[i];
    }
    __syncthreads();

    const int lane = threadIdx.x & 63;
    const int wv   = threadIdx.x >> 6;
    float* T = tb[wv];
    const float* w1s = wlds;
    const float* w2s = wlds + HH * HH;

    const int tile = blockIdx.x * 4 + wv;       // 1563 tiles of <=64 nodes
    const int base = tile * 64;
    if (base >= NN) return;
    const int n = min(base + lane, NN - 1);     // clamp ghost lanes
    const float epsv = 1.0f + epsp[0];

    float z[HH];
    const float4* hp = (const float4*)(hin + (size_t)n * HH);
    const float4* gp = (const float4*)(agg + (size_t)n * HH);
    #pragma unroll
    for (int c = 0; c < 16; ++c) {
        const float4 h4 = hp[c];
        const float4 g4 = gp[c];
        z[4*c]   = fmaf(epsv, h4.x, g4.x);
        z[4*c+1] = fmaf(epsv, h4.y, g4.y);
        z[4*c+2] = fmaf(epsv, h4.z, g4.z);
        z[4*c+3] = fmaf(epsv, h4.w, g4.w);
    }

    float v[HH];
    #pragma unroll
    for (int k = 0; k < HH; ++k) v[k] = b2[k];

    #pragma unroll 1
    for (int jb = 0; jb < 8; ++jb) {
        const int j0 = jb * 8;
        float t[8];
        #pragma unroll
        for (int q = 0; q < 8; ++q) t[q] = b1[j0 + q];
        #pragma unroll
        for (int i = 0; i < HH; ++i) {
            const float zi = z[i];
            const float4 wA = *(const float4*)&w1s[i * HH + j0];
            const float4 wB = *(const float4*)&w1s[i * HH + j0 + 4];
            t[0] = fmaf(zi, wA.x, t[0]); t[1] = fmaf(zi, wA.y, t[1]);
            t[2] = fmaf(zi, wA.z, t[2]); t[3] = fmaf(zi, wA.w, t[3]);
            t[4] = fmaf(zi, wB.x, t[4]); t[5] = fmaf(zi, wB.y, t[5]);
            t[6] = fmaf(zi, wB.z, t[6]); t[7] = fmaf(zi, wB.w, t[7]);
        }
        #pragma unroll
        for (int q = 0; q < 8; ++q) {
            const float tq = fmaxf(t[q], 0.0f);
            const float* wr = w2s + (j0 + q) * HH;
            #pragma unroll
            for (int kc = 0; kc < 16; ++kc) {
                const float4 wv4 = *(const float4*)&wr[kc * 4];
                v[kc*4+0] = fmaf(tq, wv4.x, v[kc*4+0]);
                v[kc*4+1] = fmaf(tq, wv4.y, v[kc*4+1]);
                v[kc*4+2] = fmaf(tq, wv4.z, v[kc*4+2]);
                v[kc*4+3] = fmaf(tq, wv4.w, v[kc*4+3]);
            }
        }
    }
    #pragma unroll
    for (int k = 0; k < HH; ++k) v[k] = fmaxf(v[k], 0.0f);

    const int valid = min(64, NN - base);
    float s1 = 0.0f, s2 = 0.0f;
    #pragma unroll 1
    for (int cb = 0; cb < 8; ++cb) {
        const int r = lane & 7;
        if ((lane >> 3) == cb && cb * 8 + r < valid) {
            #pragma unroll
            for (int kc = 0; kc < 16; ++kc)
                *(float4*)&T[r * 68 + kc * 4] =
                    float4{v[kc*4], v[kc*4+1], v[kc*4+2], v[kc*4+3]};
        }
        wave_lds_sync();
        const int lim = min(max(valid - cb * 8, 0), 8);
        for (int e2 = 0; e2 < lim; ++e2) {
            const int nn2 = base + cb * 8 + e2;
            const float val = T[e2 * 68 + lane];
            agg[(size_t)nn2 * HH + lane] = val;
            s1 += val;
            s2 += val * val;
        }
        wave_lds_sync();
    }
    atomicAdd(&stats[lane], s1);
    atomicAdd(&stats[64 + lane], s2);
}

// ---------------------------------------------------------------------------
__global__ void bn_finalize(float* stats) {
    int j = threadIdx.x;
    if (j < HH) {
        float mu  = stats[j] * (1.0f / NN);
        float var = stats[64 + j] * (1.0f / NN) - mu * mu;
        stats[128 + j] = mu;
        stats[192 + j] = 1.0f / sqrtf(var + 1e-5f);
    }
}

// BN apply + segmented graph-pool accumulation (batch sorted).
#define CHUNK 32
__global__ void bn_apply(
    const float* __restrict__ v, const float* __restrict__ stats,
    const float* __restrict__ gamma, const float* __restrict__ beta,
    const int* __restrict__ batch,
    float* __restrict__ hout, float* __restrict__ pooled, int layer)
{
    const int lane = threadIdx.x & 63;
    const int wv   = (blockIdx.x * blockDim.x + threadIdx.x) >> 6;
    const int n0   = wv * CHUNK;
    if (n0 >= NN) return;
    const int n1 = min(n0 + CHUNK, NN);
    const float mu = stats[128 + lane], rs = stats[192 + lane];
    const float ga = gamma[lane],       be = beta[lane];
    float acc = 0.0f;
    int cur = batch[n0];
    for (int n = n0; n < n1; ++n) {
        const int b = batch[n];                       // uniform
        const float z = (v[(size_t)n * HH + lane] - mu) * rs * ga + be;
        hout[(size_t)n * HH + lane] = z;
        if (b != cur) {                               // uniform branch
            atomicAdd(&pooled[(size_t)cur * (NL * HH) + layer * HH + lane], acc);
            acc = 0.0f; cur = b;
        }
        acc += z;
    }
    atomicAdd(&pooled[(size_t)cur * (NL * HH) + layer * HH + lane], acc);
}

// ---------------------------------------------------------------------------
__global__ __launch_bounds__(256, 1) void graph_kernel(
    const float* __restrict__ pooled, const float* __restrict__ cnt,
    const float* __restrict__ fc0_w, const float* __restrict__ fc0_b,
    const float* __restrict__ wts, const int* __restrict__ sgb,
    float* __restrict__ s_acc)
{
    __shared__ float w[NL * HH * HH];   // 48KB
    for (int i = threadIdx.x; i < NL * HH * HH; i += blockDim.x) w[i] = fc0_w[i];
    __syncthreads();
    const int lane = threadIdx.x & 63;
    const int g = blockIdx.x * 4 + (threadIdx.x >> 6);
    if (g >= NG) return;
    const float inv = 1.0f / fmaxf(cnt[g], 1.0f);
    float acc = fc0_b[lane];
    #pragma unroll
    for (int c = 0; c < NL; ++c) {
        const float a = pooled[g * (NL * HH) + c * HH + lane] * inv;
        #pragma unroll
        for (int k = 0; k < HH; ++k)
            acc = fmaf(bcastf(a, k), w[(c * HH + k) * HH + lane], acc);
    }
    const float og = fmaxf(acc, 0.0f) * wts[g];
    atomicAdd(&s_acc[sgb[g] * HH + lane], og);
}

__global__ __launch_bounds__(256, 1) void final_kernel(
    const float* __restrict__ s_acc, const float* __restrict__ norm,
    const float* __restrict__ fc1_w, const float* __restrict__ fc1_b,
    const float* __restrict__ fc2_w, const float* __restrict__ fc2_b,
    const float* __restrict__ pw, const float* __restrict__ pb,
    float* __restrict__ out)
{
    const int lane = threadIdx.x & 63;
    const int s = blockIdx.x * 4 + (threadIdx.x >> 6);
    if (s >= NSG) return;
    const float xv = s_acc[s * HH + lane] / fmaxf(norm[s], 1e-12f);
    float u = fc1_b[lane];
    #pragma unroll
    for (int k = 0; k < HH; ++k) u = fmaf(bcastf(xv, k), fc1_w[k * HH + lane], u);
    u = fmaxf(u, 0.0f);
    float v = fc2_b[lane];
    #pragma unroll
    for (int k = 0; k < HH; ++k) v = fmaf(bcastf(u, k), fc2_w[k * HH + lane], v);
    v = fmaxf(v, 0.0f);
    float o = pb[lane & 31];
    #pragma unroll
    for (int k = 0; k < HH; ++k) o = fmaf(bcastf(v, k), pw[k * NOUT + (lane & 31)], o);
    if (lane < NOUT) out[s * NOUT + lane] = o;
}

// ---------------------------------------------------------------------------
extern "C" void kernel_launch(void* const* d_in, const int* in_sizes, int n_in,
                              void* d_out, int out_size, void* d_ws, size_t ws_size,
                              hipStream_t stream)
{
    const float* x        = (const float*)d_in[0];
    const int*   eidx     = (const int*)d_in[1];
    const float* eattr    = (const float*)d_in[2];
    const int*   batch    = (const int*)d_in[3];
    const float* weights  = (const float*)d_in[4];
    const int*   sgb      = (const int*)d_in[5];
    const float* be_w1    = (const float*)d_in[6];
    const float* be_b1    = (const float*)d_in[7];
    const float* be_w2    = (const float*)d_in[8];
    const float* be_b2    = (const float*)d_in[9];
    const float* mlp_w1   = (const float*)d_in[10];
    const float* mlp_b1   = (const float*)d_in[11];
    const float* mlp_w2   = (const float*)d_in[12];
    const float* mlp_b2   = (const float*)d_in[13];
    const float* eps      = (const float*)d_in[14];
    const float* bn_gamma = (const float*)d_in[15];
    const float* bn_beta  = (const float*)d_in[16];
    const float* fc0_w    = (const float*)d_in[17];
    const float* fc0_b    = (const float*)d_in[18];
    const float* fc1_w    = (const float*)d_in[19];
    const float* fc1_b    = (const float*)d_in[20];
    const float* fc2_w    = (const float*)d_in[21];
    const float* fc2_b    = (const float*)d_in[22];
    const float* pred_w   = (const float*)d_in[23];
    const float* pred_b   = (const float*)d_in[24];
    float* out = (float*)d_out;

    float* ws     = (float*)d_ws;
    float* h_buf  = ws;                               // NN*64
    float* agg    = ws + (size_t)NN * HH;             // NN*64 (also holds v)
    float* pooled = ws + (size_t)NN * HH * 2;         // NG*192
    float* cnt    = pooled + (size_t)NG * NL * HH;    // NG
    float* stats  = cnt + NG;                         // 256
    float* s_acc  = stats + 256;                      // NSG*64
    float* norm   = s_acc + (size_t)NSG * HH;         // NSG

    size_t acc_floats = (size_t)NG * NL * HH + NG + 256 + (size_t)NSG * HH + NSG;
    hipMemsetAsync(pooled, 0, acc_floats * sizeof(float), stream);

    cnt_kernel<<<(NN + 255) / 256, 256, 0, stream>>>(batch, cnt);
    norm_kernel<<<4, 256, 0, stream>>>(sgb, weights, norm);

    const float* hin = x;
    const int edge_tiles = NE / 64;                   // 15625
    const int edge_blocks = (edge_tiles + 3) / 4;
    const int node_tiles = (NN + 63) / 64;            // 1563
    const int node_blocks = (node_tiles + 3) / 4;
    const int bn_waves  = (NN + CHUNK - 1) / CHUNK;
    const int bn_blocks = (bn_waves + 3) / 4;
    for (int l = 0; l < NL; ++l) {
        hipMemsetAsync(agg, 0, (size_t)NN * HH * sizeof(float), stream);
        hipMemsetAsync(stats, 0, 256 * sizeof(float), stream);
        edge_fused<<<edge_blocks, 256, 0, stream>>>(
            hin, eattr, eidx,
            be_w1 + l * EF * HH, be_b1 + l * HH,
            be_w2 + l * HH * HH, be_b2 + l * HH, agg);
        node_fused<<<node_blocks, 256, 0, stream>>>(
            hin, agg,
            mlp_w1 + l * HH * HH, mlp_b1 + l * HH,
            mlp_w2 + l * HH * HH, mlp_b2 + l * HH,
            eps + l, stats);
        bn_finalize<<<1, 64, 0, stream>>>(stats);
        bn_apply<<<bn_blocks, 256, 0, stream>>>(
            agg, stats, bn_gamma + l * HH, bn_beta + l * HH,
            batch, h_buf, pooled, l);
        hin = h_buf;
    }

    graph_kernel<<<NG / 4, 256, 0, stream>>>(pooled, cnt, fc0_w, fc0_b,
                                             weights, sgb, s_acc);
    final_kernel<<<NSG / 4, 256, 0, stream>>>(s_acc, norm, fc1_w, fc1_b,
                                              fc2_w, fc2_b, pred_w, pred_b, out);
}

// Round 5
// 1337.622 us; speedup vs baseline: 1.5571x; 1.5571x over previous
//
#include <hip/hip_runtime.h>

#define NN 100000      // nodes
#define NE 1000000     // edges
#define NG 1024        // graphs
#define NSG 128        // subgraphs
#define EF 32          // edge feature dim
#define HH 64          // hidden
#define NOUT 32        // output classes
#define NL 3           // layers

typedef __attribute__((ext_vector_type(8))) short bf16x8;
typedef __attribute__((ext_vector_type(4))) float f32x4;

// wave-uniform broadcast of lane l's value (v_readlane -> SGPR)
__device__ __forceinline__ float bcastf(float v, int l) {
    return __int_as_float(__builtin_amdgcn_readlane(__float_as_int(v), l));
}

// fp32 -> bf16 (RNE)
__device__ __forceinline__ short f2bf(float x) {
    unsigned u = __float_as_uint(x);
    u += 0x7FFFu + ((u >> 16) & 1u);
    return (short)(u >> 16);
}

// wave-internal LDS producer->consumer handoff (no cross-wave sharing)
__device__ __forceinline__ void wave_lds_sync() {
    __builtin_amdgcn_wave_barrier();
    asm volatile("s_waitcnt lgkmcnt(0)" ::: "memory");
    __builtin_amdgcn_wave_barrier();
}

// ---------------------------------------------------------------------------
__global__ void cnt_kernel(const int* __restrict__ batch, float* __restrict__ cnt) {
    int i = blockIdx.x * blockDim.x + threadIdx.x;
    if (i < NN) atomicAdd(&cnt[batch[i]], 1.0f);
}

__global__ void norm_kernel(const int* __restrict__ sgb, const float* __restrict__ w,
                            float* __restrict__ norm) {
    int i = blockIdx.x * blockDim.x + threadIdx.x;
    if (i < NG) atomicAdd(&norm[sgb[i]], w[i]);
}

// ---------------------------------------------------------------------------
// Edge pass via MFMA (bf16 in, fp32 accum). Per wave, 16-edge groups:
//   GEMM1 (4x mfma_16x16x32): t = relu(ea@W1+b1)    [16x64]
//   LDS roundtrip: C-layout -> A-layout (m120-verified choreography)
//   GEMM2 (8x mfma): emb = t@W2+b2                   [16x64]
//   phase 2 (unchanged R3 profile): msg = relu(h[src]+emb); agg[dst] += msg
#define GPW 4   // 16-edge groups per wave
__global__ __launch_bounds__(256, 4) void edge_mfma(
    const float* __restrict__ hin,       // [NN,64]
    const float* __restrict__ eattr,     // [NE,32]
    const int*   __restrict__ eidx,      // [2,NE]
    const float* __restrict__ w1,        // [32,64]
    const float* __restrict__ b1,        // [64]
    const float* __restrict__ w2,        // [64,64]
    const float* __restrict__ b2,        // [64]
    float*       __restrict__ agg)       // [NN,64]
{
    __shared__ float ldsbuf[4][1088];    // 4352 B per wave (t bf16 / emb fp32 union)
    const int lane = threadIdx.x & 63;
    const int wv   = threadIdx.x >> 6;
    const int col  = lane & 15;          // MFMA: B col / C col / A row
    const int quad = lane >> 4;
    float* EM = ldsbuf[wv];              // emb fp32 [16][68]
    short* T  = (short*)EM;              // t bf16 [16][72] (2304 B, overlap is sequenced)

    // --- weight fragments, built once per wave ---
    // B-frag layout: n = col, k = quad*8 + j
    bf16x8 B1f[4];
    #pragma unroll
    for (int nt = 0; nt < 4; ++nt)
        #pragma unroll
        for (int j = 0; j < 8; ++j)
            B1f[nt][j] = f2bf(w1[(quad * 8 + j) * HH + nt * 16 + col]);
    bf16x8 B2f[2][4];
    #pragma unroll
    for (int ks = 0; ks < 2; ++ks)
        #pragma unroll
        for (int nt = 0; nt < 4; ++nt)
            #pragma unroll
            for (int j = 0; j < 8; ++j)
                B2f[ks][nt][j] = f2bf(w2[(ks * 32 + quad * 8 + j) * HH + nt * 16 + col]);
    float b1v[4], b2v[4];
    #pragma unroll
    for (int nt = 0; nt < 4; ++nt) {
        b1v[nt] = b1[nt * 16 + col];
        b2v[nt] = b2[nt * 16 + col];
    }

    const int wave_id = (blockIdx.x * 256 + (int)threadIdx.x) >> 6;
    #pragma unroll 1
    for (int gi = 0; gi < GPW; ++gi) {
        const int grp = wave_id * GPW + gi;
        if (grp >= NE / 16) break;                 // uniform
        const int e0 = grp * 16;

        // A1-frag: eattr[e0+col][quad*8 .. +7]  (8 consecutive floats)
        const float* arow = eattr + (size_t)(e0 + col) * EF + quad * 8;
        const float4 a0 = *(const float4*)arow;
        const float4 a1 = *(const float4*)(arow + 4);
        bf16x8 A1;
        A1[0] = f2bf(a0.x); A1[1] = f2bf(a0.y); A1[2] = f2bf(a0.z); A1[3] = f2bf(a0.w);
        A1[4] = f2bf(a1.x); A1[5] = f2bf(a1.y); A1[6] = f2bf(a1.z); A1[7] = f2bf(a1.w);

        // GEMM1 + bias + relu -> T (bf16, A2-readable layout, row stride 72)
        #pragma unroll
        for (int nt = 0; nt < 4; ++nt) {
            f32x4 C = {0.f, 0.f, 0.f, 0.f};
            C = __builtin_amdgcn_mfma_f32_16x16x32_bf16(A1, B1f[nt], C, 0, 0, 0);
            #pragma unroll
            for (int r = 0; r < 4; ++r) {
                const float tv = fmaxf(C[r] + b1v[nt], 0.0f);
                T[(quad * 4 + r) * 72 + nt * 16 + col] = f2bf(tv);
            }
        }
        wave_lds_sync();

        // A2-frags: t[m=col][ks*32 + quad*8 .. +7]  (16B-aligned: 144m+64ks+16q)
        bf16x8 A2_0 = *(const bf16x8*)&T[col * 72 + 0  + quad * 8];
        bf16x8 A2_1 = *(const bf16x8*)&T[col * 72 + 32 + quad * 8];
        wave_lds_sync();

        // GEMM2 + bias -> EM (fp32 [16][68])
        #pragma unroll
        for (int nt = 0; nt < 4; ++nt) {
            f32x4 C = {0.f, 0.f, 0.f, 0.f};
            C = __builtin_amdgcn_mfma_f32_16x16x32_bf16(A2_0, B2f[0][nt], C, 0, 0, 0);
            C = __builtin_amdgcn_mfma_f32_16x16x32_bf16(A2_1, B2f[1][nt], C, 0, 0, 0);
            #pragma unroll
            for (int r = 0; r < 4; ++r)
                EM[(quad * 4 + r) * 68 + nt * 16 + col] = C[r] + b2v[nt];
        }
        wave_lds_sync();

        // phase 2: feature-parallel gather + relu + scatter (lane = feature)
        #pragma unroll 4
        for (int e2 = 0; e2 < 16; ++e2) {
            const int src = eidx[e0 + e2];
            const int dst = eidx[NE + e0 + e2];
            const float emv = EM[e2 * 68 + lane];
            const float msg = fmaxf(hin[(size_t)src * HH + lane] + emv, 0.0f);
            atomicAdd(&agg[(size_t)dst * HH + lane], msg);
        }
        wave_lds_sync();
    }
}

// ---------------------------------------------------------------------------
// Node pass, lane-owns-node; LDS-staged weights; 8-node chunk transpose for
// coalesced in-place store + BN sum/sumsq. (R4 version, unchanged.)
__global__ __launch_bounds__(256, 3) void node_fused(
    const float* __restrict__ hin,
    float*       agg,                    // in: agg, out: v (same rows only)
    const float* __restrict__ w1, const float* __restrict__ b1,
    const float* __restrict__ w2, const float* __restrict__ b2,
    const float* __restrict__ epsp,
    float*       __restrict__ stats)     // [0:64] sum, [64:128] sumsq
{
    __shared__ float wlds[2 * HH * HH];         // 32 KB
    __shared__ float tb[4][8 * 68];             // 8.5 KB
    {
        const float4* s1 = (const float4*)w1;
        const float4* s2 = (const float4*)w2;
        float4* d = (float4*)wlds;
        for (int i = threadIdx.x; i < 1024; i += 256) d[i] = s1[i];
        for (int i = threadIdx.x; i < 1024; i += 256) d[1024 + i] = s2[i];
    }
    __syncthreads();

    const int lane = threadIdx.x & 63;
    const int wv   = threadIdx.x >> 6;
    float* T = tb[wv];
    const float* w1s = wlds;
    const float* w2s = wlds + HH * HH;

    const int tile = blockIdx.x * 4 + wv;
    const int base = tile * 64;
    if (base >= NN) return;
    const int n = min(base + lane, NN - 1);
    const float epsv = 1.0f + epsp[0];

    float z[HH];
    const float4* hp = (const float4*)(hin + (size_t)n * HH);
    const float4* gp = (const float4*)(agg + (size_t)n * HH);
    #pragma unroll
    for (int c = 0; c < 16; ++c) {
        const float4 h4 = hp[c];
        const float4 g4 = gp[c];
        z[4*c]   = fmaf(epsv, h4.x, g4.x);
        z[4*c+1] = fmaf(epsv, h4.y, g4.y);
        z[4*c+2] = fmaf(epsv, h4.z, g4.z);
        z[4*c+3] = fmaf(epsv, h4.w, g4.w);
    }

    float v[HH];
    #pragma unroll
    for (int k = 0; k < HH; ++k) v[k] = b2[k];

    #pragma unroll 1
    for (int jb = 0; jb < 8; ++jb) {
        const int j0 = jb * 8;
        float t[8];
        #pragma unroll
        for (int q = 0; q < 8; ++q) t[q] = b1[j0 + q];
        #pragma unroll
        for (int i = 0; i < HH; ++i) {
            const float zi = z[i];
            const float4 wA = *(const float4*)&w1s[i * HH + j0];
            const float4 wB = *(const float4*)&w1s[i * HH + j0 + 4];
            t[0] = fmaf(zi, wA.x, t[0]); t[1] = fmaf(zi, wA.y, t[1]);
            t[2] = fmaf(zi, wA.z, t[2]); t[3] = fmaf(zi, wA.w, t[3]);
            t[4] = fmaf(zi, wB.x, t[4]); t[5] = fmaf(zi, wB.y, t[5]);
            t[6] = fmaf(zi, wB.z, t[6]); t[7] = fmaf(zi, wB.w, t[7]);
        }
        #pragma unroll
        for (int q = 0; q < 8; ++q) {
            const float tq = fmaxf(t[q], 0.0f);
            const float* wr = w2s + (j0 + q) * HH;
            #pragma unroll
            for (int kc = 0; kc < 16; ++kc) {
                const float4 wv4 = *(const float4*)&wr[kc * 4];
                v[kc*4+0] = fmaf(tq, wv4.x, v[kc*4+0]);
                v[kc*4+1] = fmaf(tq, wv4.y, v[kc*4+1]);
                v[kc*4+2] = fmaf(tq, wv4.z, v[kc*4+2]);
                v[kc*4+3] = fmaf(tq, wv4.w, v[kc*4+3]);
            }
        }
    }
    #pragma unroll
    for (int k = 0; k < HH; ++k) v[k] = fmaxf(v[k], 0.0f);

    const int valid = min(64, NN - base);
    float s1 = 0.0f, s2 = 0.0f;
    #pragma unroll 1
    for (int cb = 0; cb < 8; ++cb) {
        const int r = lane & 7;
        if ((lane >> 3) == cb && cb * 8 + r < valid) {
            #pragma unroll
            for (int kc = 0; kc < 16; ++kc)
                *(float4*)&T[r * 68 + kc * 4] =
                    float4{v[kc*4], v[kc*4+1], v[kc*4+2], v[kc*4+3]};
        }
        wave_lds_sync();
        const int lim = min(max(valid - cb * 8, 0), 8);
        for (int e2 = 0; e2 < lim; ++e2) {
            const int nn2 = base + cb * 8 + e2;
            const float val = T[e2 * 68 + lane];
            agg[(size_t)nn2 * HH + lane] = val;
            s1 += val;
            s2 += val * val;
        }
        wave_lds_sync();
    }
    atomicAdd(&stats[lane], s1);
    atomicAdd(&stats[64 + lane], s2);
}

// ---------------------------------------------------------------------------
__global__ void bn_finalize(float* stats) {
    int j = threadIdx.x;
    if (j < HH) {
        float mu  = stats[j] * (1.0f / NN);
        float var = stats[64 + j] * (1.0f / NN) - mu * mu;
        stats[128 + j] = mu;
        stats[192 + j] = 1.0f / sqrtf(var + 1e-5f);
    }
}

// BN apply + segmented graph-pool accumulation (batch sorted).
#define CHUNK 32
__global__ void bn_apply(
    const float* __restrict__ v, const float* __restrict__ stats,
    const float* __restrict__ gamma, const float* __restrict__ beta,
    const int* __restrict__ batch,
    float* __restrict__ hout, float* __restrict__ pooled, int layer)
{
    const int lane = threadIdx.x & 63;
    const int wv   = (blockIdx.x * blockDim.x + threadIdx.x) >> 6;
    const int n0   = wv * CHUNK;
    if (n0 >= NN) return;
    const int n1 = min(n0 + CHUNK, NN);
    const float mu = stats[128 + lane], rs = stats[192 + lane];
    const float ga = gamma[lane],       be = beta[lane];
    float acc = 0.0f;
    int cur = batch[n0];
    for (int n = n0; n < n1; ++n) {
        const int b = batch[n];                       // uniform
        const float z = (v[(size_t)n * HH + lane] - mu) * rs * ga + be;
        hout[(size_t)n * HH + lane] = z;
        if (b != cur) {                               // uniform branch
            atomicAdd(&pooled[(size_t)cur * (NL * HH) + layer * HH + lane], acc);
            acc = 0.0f; cur = b;
        }
        acc += z;
    }
    atomicAdd(&pooled[(size_t)cur * (NL * HH) + layer * HH + lane], acc);
}

// ---------------------------------------------------------------------------
__global__ __launch_bounds__(256, 1) void graph_kernel(
    const float* __restrict__ pooled, const float* __restrict__ cnt,
    const float* __restrict__ fc0_w, const float* __restrict__ fc0_b,
    const float* __restrict__ wts, const int* __restrict__ sgb,
    float* __restrict__ s_acc)
{
    __shared__ float w[NL * HH * HH];   // 48KB
    for (int i = threadIdx.x; i < NL * HH * HH; i += blockDim.x) w[i] = fc0_w[i];
    __syncthreads();
    const int lane = threadIdx.x & 63;
    const int g = blockIdx.x * 4 + (threadIdx.x >> 6);
    if (g >= NG) return;
    const float inv = 1.0f / fmaxf(cnt[g], 1.0f);
    float acc = fc0_b[lane];
    #pragma unroll
    for (int c = 0; c < NL; ++c) {
        const float a = pooled[g * (NL * HH) + c * HH + lane] * inv;
        #pragma unroll
        for (int k = 0; k < HH; ++k)
            acc = fmaf(bcastf(a, k), w[(c * HH + k) * HH + lane], acc);
    }
    const float og = fmaxf(acc, 0.0f) * wts[g];
    atomicAdd(&s_acc[sgb[g] * HH + lane], og);
}

__global__ __launch_bounds__(256, 1) void final_kernel(
    const float* __restrict__ s_acc, const float* __restrict__ norm,
    const float* __restrict__ fc1_w, const float* __restrict__ fc1_b,
    const float* __restrict__ fc2_w, const float* __restrict__ fc2_b,
    const float* __restrict__ pw, const float* __restrict__ pb,
    float* __restrict__ out)
{
    const int lane = threadIdx.x & 63;
    const int s = blockIdx.x * 4 + (threadIdx.x >> 6);
    if (s >= NSG) return;
    const float xv = s_acc[s * HH + lane] / fmaxf(norm[s], 1e-12f);
    float u = fc1_b[lane];
    #pragma unroll
    for (int k = 0; k < HH; ++k) u = fmaf(bcastf(xv, k), fc1_w[k * HH + lane], u);
    u = fmaxf(u, 0.0f);
    float v = fc2_b[lane];
    #pragma unroll
    for (int k = 0; k < HH; ++k) v = fmaf(bcastf(u, k), fc2_w[k * HH + lane], v);
    v = fmaxf(v, 0.0f);
    float o = pb[lane & 31];
    #pragma unroll
    for (int k = 0; k < HH; ++k) o = fmaf(bcastf(v, k), pw[k * NOUT + (lane & 31)], o);
    if (lane < NOUT) out[s * NOUT + lane] = o;
}

// ---------------------------------------------------------------------------
extern "C" void kernel_launch(void* const* d_in, const int* in_sizes, int n_in,
                              void* d_out, int out_size, void* d_ws, size_t ws_size,
                              hipStream_t stream)
{
    const float* x        = (const float*)d_in[0];
    const int*   eidx     = (const int*)d_in[1];
    const float* eattr    = (const float*)d_in[2];
    const int*   batch    = (const int*)d_in[3];
    const float* weights  = (const float*)d_in[4];
    const int*   sgb      = (const int*)d_in[5];
    const float* be_w1    = (const float*)d_in[6];
    const float* be_b1    = (const float*)d_in[7];
    const float* be_w2    = (const float*)d_in[8];
    const float* be_b2    = (const float*)d_in[9];
    const float* mlp_w1   = (const float*)d_in[10];
    const float* mlp_b1   = (const float*)d_in[11];
    const float* mlp_w2   = (const float*)d_in[12];
    const float* mlp_b2   = (const float*)d_in[13];
    const float* eps      = (const float*)d_in[14];
    const float* bn_gamma = (const float*)d_in[15];
    const float* bn_beta  = (const float*)d_in[16];
    const float* fc0_w    = (const float*)d_in[17];
    const float* fc0_b    = (const float*)d_in[18];
    const float* fc1_w    = (const float*)d_in[19];
    const float* fc1_b    = (const float*)d_in[20];
    const float* fc2_w    = (const float*)d_in[21];
    const float* fc2_b    = (const float*)d_in[22];
    const float* pred_w   = (const float*)d_in[23];
    const float* pred_b   = (const float*)d_in[24];
    float* out = (float*)d_out;

    float* ws     = (float*)d_ws;
    float* h_buf  = ws;                               // NN*64
    float* agg    = ws + (size_t)NN * HH;             // NN*64 (also holds v)
    float* pooled = ws + (size_t)NN * HH * 2;         // NG*192
    float* cnt    = pooled + (size_t)NG * NL * HH;    // NG
    float* stats  = cnt + NG;                         // 256
    float* s_acc  = stats + 256;                      // NSG*64
    float* norm   = s_acc + (size_t)NSG * HH;         // NSG

    size_t acc_floats = (size_t)NG * NL * HH + NG + 256 + (size_t)NSG * HH + NSG;
    hipMemsetAsync(pooled, 0, acc_floats * sizeof(float), stream);

    cnt_kernel<<<(NN + 255) / 256, 256, 0, stream>>>(batch, cnt);
    norm_kernel<<<4, 256, 0, stream>>>(sgb, weights, norm);

    const float* hin = x;
    const int egroups = NE / 16;                      // 62500
    const int ewaves  = (egroups + GPW - 1) / GPW;    // 15625
    const int eblocks = (ewaves + 3) / 4;             // 3907
    const int node_tiles = (NN + 63) / 64;
    const int node_blocks = (node_tiles + 3) / 4;
    const int bn_waves  = (NN + CHUNK - 1) / CHUNK;
    const int bn_blocks = (bn_waves + 3) / 4;
    for (int l = 0; l < NL; ++l) {
        hipMemsetAsync(agg, 0, (size_t)NN * HH * sizeof(float), stream);
        hipMemsetAsync(stats, 0, 256 * sizeof(float), stream);
        edge_mfma<<<eblocks, 256, 0, stream>>>(
            hin, eattr, eidx,
            be_w1 + l * EF * HH, be_b1 + l * HH,
            be_w2 + l * HH * HH, be_b2 + l * HH, agg);
        node_fused<<<node_blocks, 256, 0, stream>>>(
            hin, agg,
            mlp_w1 + l * HH * HH, mlp_b1 + l * HH,
            mlp_w2 + l * HH * HH, mlp_b2 + l * HH,
            eps + l, stats);
        bn_finalize<<<1, 64, 0, stream>>>(stats);
        bn_apply<<<bn_blocks, 256, 0, stream>>>(
            agg, stats, bn_gamma + l * HH, bn_beta + l * HH,
            batch, h_buf, pooled, l);
        hin = h_buf;
    }

    graph_kernel<<<NG / 4, 256, 0, stream>>>(pooled, cnt, fc0_w, fc0_b,
                                             weights, sgb, s_acc);
    final_kernel<<<NSG / 4, 256, 0, stream>>>(s_acc, norm, fc1_w, fc1_b,
                                              fc2_w, fc2_b, pred_w, pred_b, out);
}

// Round 6
// 1203.330 us; speedup vs baseline: 1.7308x; 1.1116x over previous
//
#include <hip/hip_runtime.h>

#define NN 100000      // nodes
#define NE 1000000     // edges
#define NG 1024        // graphs
#define NSG 128        // subgraphs
#define EF 32          // edge feature dim
#define HH 64          // hidden
#define NOUT 32        // output classes
#define NL 3           // layers

typedef __attribute__((ext_vector_type(8))) short bf16x8;
typedef __attribute__((ext_vector_type(4))) float f32x4;

// wave-uniform broadcast of lane l's value (v_readlane -> SGPR)
__device__ __forceinline__ float bcastf(float v, int l) {
    return __int_as_float(__builtin_amdgcn_readlane(__float_as_int(v), l));
}

// fp32 -> bf16 (RNE)
__device__ __forceinline__ short f2bf(float x) {
    unsigned u = __float_as_uint(x);
    u += 0x7FFFu + ((u >> 16) & 1u);
    return (short)(u >> 16);
}

// wave-internal LDS producer->consumer handoff (no cross-wave sharing)
__device__ __forceinline__ void wave_lds_sync() {
    __builtin_amdgcn_wave_barrier();
    asm volatile("s_waitcnt lgkmcnt(0)" ::: "memory");
    __builtin_amdgcn_wave_barrier();
}

// ---------------------------------------------------------------------------
__global__ void cnt_kernel(const int* __restrict__ batch, float* __restrict__ cnt) {
    int i = blockIdx.x * blockDim.x + threadIdx.x;
    if (i < NN) atomicAdd(&cnt[batch[i]], 1.0f);
}

__global__ void norm_kernel(const int* __restrict__ sgb, const float* __restrict__ w,
                            float* __restrict__ norm) {
    int i = blockIdx.x * blockDim.x + threadIdx.x;
    if (i < NG) atomicAdd(&norm[sgb[i]], w[i]);
}

// --------------------------- edge counting-sort ----------------------------
__global__ void hist_kernel(const int* __restrict__ eidx, int* __restrict__ off) {
    int e = blockIdx.x * 256 + threadIdx.x;
    if (e < NE) atomicAdd(&off[eidx[NE + e]], 1);
}

__global__ void scan1(int* __restrict__ off, int* __restrict__ bsum) {
    __shared__ int s[256];
    const int i = blockIdx.x * 256 + threadIdx.x;
    const int v = (i < NN) ? off[i] : 0;
    s[threadIdx.x] = v; __syncthreads();
    for (int d = 1; d < 256; d <<= 1) {
        const int t = (threadIdx.x >= d) ? s[threadIdx.x - d] : 0;
        __syncthreads(); s[threadIdx.x] += t; __syncthreads();
    }
    if (i < NN) off[i] = s[threadIdx.x] - v;          // exclusive
    if (threadIdx.x == 255) bsum[blockIdx.x] = s[255];
}

__global__ void scan2(int* __restrict__ bsum, int nb) {
    __shared__ int s[512];
    const int v = (threadIdx.x < nb) ? bsum[threadIdx.x] : 0;
    s[threadIdx.x] = v; __syncthreads();
    for (int d = 1; d < 512; d <<= 1) {
        const int t = (threadIdx.x >= d) ? s[threadIdx.x - d] : 0;
        __syncthreads(); s[threadIdx.x] += t; __syncthreads();
    }
    if (threadIdx.x < nb) bsum[threadIdx.x] = s[threadIdx.x] - v;  // exclusive
}

__global__ void scan3(int* __restrict__ off, const int* __restrict__ bsum) {
    const int i = blockIdx.x * 256 + threadIdx.x;
    if (i < NN) off[i] += bsum[blockIdx.x];
}

__global__ void scatter_kernel(const int* __restrict__ eidx, int* __restrict__ off,
                               int* __restrict__ perm_s, int* __restrict__ src_s,
                               int* __restrict__ dst_s) {
    int e = blockIdx.x * 256 + threadIdx.x;
    if (e < NE) {
        const int d = eidx[NE + e];
        const int p = atomicAdd(&off[d], 1);
        perm_s[p] = e;
        src_s[p]  = eidx[e];
        dst_s[p]  = d;
    }
}

// ---------------------------------------------------------------------------
// Edge pass via MFMA over dst-SORTED edges; phase 2 does segmented per-dst
// accumulation in registers, flushing ONE atomicAdd per distinct dst
// (~8 flushes per 64-edge wave at avg degree 10, vs 64 before).
#define GPW 4   // 16-edge groups per wave
__global__ __launch_bounds__(256, 4) void edge_mfma(
    const float* __restrict__ hin,       // [NN,64]
    const float* __restrict__ eattr,     // [NE,32]
    const int*   __restrict__ perm_s,    // [NE] sorted->orig edge id
    const int*   __restrict__ src_s,     // [NE] src of sorted edge
    const int*   __restrict__ dst_s,     // [NE] dst of sorted edge (nondecreasing)
    const float* __restrict__ w1,        // [32,64]
    const float* __restrict__ b1,        // [64]
    const float* __restrict__ w2,        // [64,64]
    const float* __restrict__ b2,        // [64]
    float*       __restrict__ agg)       // [NN,64]
{
    __shared__ float ldsbuf[4][1088];    // per-wave (t bf16 / emb fp32 union)
    const int lane = threadIdx.x & 63;
    const int wv   = threadIdx.x >> 6;
    const int col  = lane & 15;          // MFMA: B col / C col / A row
    const int quad = lane >> 4;
    float* EM = ldsbuf[wv];              // emb fp32 [16][68]
    short* T  = (short*)EM;              // t bf16 [16][72]

    // --- weight fragments, built once per wave ---
    bf16x8 B1f[4];
    #pragma unroll
    for (int nt = 0; nt < 4; ++nt)
        #pragma unroll
        for (int j = 0; j < 8; ++j)
            B1f[nt][j] = f2bf(w1[(quad * 8 + j) * HH + nt * 16 + col]);
    bf16x8 B2f[2][4];
    #pragma unroll
    for (int ks = 0; ks < 2; ++ks)
        #pragma unroll
        for (int nt = 0; nt < 4; ++nt)
            #pragma unroll
            for (int j = 0; j < 8; ++j)
                B2f[ks][nt][j] = f2bf(w2[(ks * 32 + quad * 8 + j) * HH + nt * 16 + col]);
    float b1v[4], b2v[4];
    #pragma unroll
    for (int nt = 0; nt < 4; ++nt) {
        b1v[nt] = b1[nt * 16 + col];
        b2v[nt] = b2[nt * 16 + col];
    }

    const int wid = __builtin_amdgcn_readfirstlane(
        (blockIdx.x * 256 + (int)threadIdx.x) >> 6);

    int   cur = -1;       // current dst segment (wave-uniform)
    float acc = 0.0f;     // per-lane feature accumulator

    #pragma unroll 1
    for (int gi = 0; gi < GPW; ++gi) {
        const int grp = wid * GPW + gi;
        if (grp >= NE / 16) break;                 // uniform
        const int e0 = grp * 16;

        // A1-frag: eattr[perm_s[e0+col]][quad*8 .. +7]
        const int pe = perm_s[e0 + col];
        const float* arow = eattr + (size_t)pe * EF + quad * 8;
        const float4 a0 = *(const float4*)arow;
        const float4 a1 = *(const float4*)(arow + 4);
        bf16x8 A1;
        A1[0] = f2bf(a0.x); A1[1] = f2bf(a0.y); A1[2] = f2bf(a0.z); A1[3] = f2bf(a0.w);
        A1[4] = f2bf(a1.x); A1[5] = f2bf(a1.y); A1[6] = f2bf(a1.z); A1[7] = f2bf(a1.w);

        // GEMM1 + bias + relu -> T (bf16, A2-readable layout, row stride 72)
        #pragma unroll
        for (int nt = 0; nt < 4; ++nt) {
            f32x4 C = {0.f, 0.f, 0.f, 0.f};
            C = __builtin_amdgcn_mfma_f32_16x16x32_bf16(A1, B1f[nt], C, 0, 0, 0);
            #pragma unroll
            for (int r = 0; r < 4; ++r) {
                const float tv = fmaxf(C[r] + b1v[nt], 0.0f);
                T[(quad * 4 + r) * 72 + nt * 16 + col] = f2bf(tv);
            }
        }
        wave_lds_sync();

        // A2-frags: t[m=col][ks*32 + quad*8 .. +7]
        bf16x8 A2_0 = *(const bf16x8*)&T[col * 72 + 0  + quad * 8];
        bf16x8 A2_1 = *(const bf16x8*)&T[col * 72 + 32 + quad * 8];
        wave_lds_sync();

        // GEMM2 + bias -> EM (fp32 [16][68])
        #pragma unroll
        for (int nt = 0; nt < 4; ++nt) {
            f32x4 C = {0.f, 0.f, 0.f, 0.f};
            C = __builtin_amdgcn_mfma_f32_16x16x32_bf16(A2_0, B2f[0][nt], C, 0, 0, 0);
            C = __builtin_amdgcn_mfma_f32_16x16x32_bf16(A2_1, B2f[1][nt], C, 0, 0, 0);
            #pragma unroll
            for (int r = 0; r < 4; ++r)
                EM[(quad * 4 + r) * 68 + nt * 16 + col] = C[r] + b2v[nt];
        }
        wave_lds_sync();

        // phase 2: segmented gather + relu + accumulate; flush on dst change
        #pragma unroll 4
        for (int e2 = 0; e2 < 16; ++e2) {
            const int d   = dst_s[e0 + e2];        // uniform (readfirstlane'd base)
            const int src = src_s[e0 + e2];
            const float emv = EM[e2 * 68 + lane];
            const float msg = fmaxf(hin[(size_t)src * HH + lane] + emv, 0.0f);
            if (d != cur) {                        // uniform branch
                if (cur >= 0) atomicAdd(&agg[(size_t)cur * HH + lane], acc);
                acc = 0.0f; cur = d;
            }
            acc += msg;
        }
        wave_lds_sync();
    }
    if (cur >= 0) atomicAdd(&agg[(size_t)cur * HH + lane], acc);
}

// ---------------------------------------------------------------------------
// Node pass, lane-owns-node; LDS-staged weights; 8-node chunk transpose for
// coalesced in-place store + BN sum/sumsq. (unchanged)
__global__ __launch_bounds__(256, 3) void node_fused(
    const float* __restrict__ hin,
    float*       agg,                    // in: agg, out: v (same rows only)
    const float* __restrict__ w1, const float* __restrict__ b1,
    const float* __restrict__ w2, const float* __restrict__ b2,
    const float* __restrict__ epsp,
    float*       __restrict__ stats)     // [0:64] sum, [64:128] sumsq
{
    __shared__ float wlds[2 * HH * HH];         // 32 KB
    __shared__ float tb[4][8 * 68];             // 8.5 KB
    {
        const float4* s1 = (const float4*)w1;
        const float4* s2 = (const float4*)w2;
        float4* d = (float4*)wlds;
        for (int i = threadIdx.x; i < 1024; i += 256) d[i] = s1[i];
        for (int i = threadIdx.x; i < 1024; i += 256) d[1024 + i] = s2[i];
    }
    __syncthreads();

    const int lane = threadIdx.x & 63;
    const int wv   = threadIdx.x >> 6;
    float* T = tb[wv];
    const float* w1s = wlds;
    const float* w2s = wlds + HH * HH;

    const int tile = blockIdx.x * 4 + wv;
    const int base = tile * 64;
    if (base >= NN) return;
    const int n = min(base + lane, NN - 1);
    const float epsv = 1.0f + epsp[0];

    float z[HH];
    const float4* hp = (const float4*)(hin + (size_t)n * HH);
    const float4* gp = (const float4*)(agg + (size_t)n * HH);
    #pragma unroll
    for (int c = 0; c < 16; ++c) {
        const float4 h4 = hp[c];
        const float4 g4 = gp[c];
        z[4*c]   = fmaf(epsv, h4.x, g4.x);
        z[4*c+1] = fmaf(epsv, h4.y, g4.y);
        z[4*c+2] = fmaf(epsv, h4.z, g4.z);
        z[4*c+3] = fmaf(epsv, h4.w, g4.w);
    }

    float v[HH];
    #pragma unroll
    for (int k = 0; k < HH; ++k) v[k] = b2[k];

    #pragma unroll 1
    for (int jb = 0; jb < 8; ++jb) {
        const int j0 = jb * 8;
        float t[8];
        #pragma unroll
        for (int q = 0; q < 8; ++q) t[q] = b1[j0 + q];
        #pragma unroll
        for (int i = 0; i < HH; ++i) {
            const float zi = z[i];
            const float4 wA = *(const float4*)&w1s[i * HH + j0];
            const float4 wB = *(const float4*)&w1s[i * HH + j0 + 4];
            t[0] = fmaf(zi, wA.x, t[0]); t[1] = fmaf(zi, wA.y, t[1]);
            t[2] = fmaf(zi, wA.z, t[2]); t[3] = fmaf(zi, wA.w, t[3]);
            t[4] = fmaf(zi, wB.x, t[4]); t[5] = fmaf(zi, wB.y, t[5]);
            t[6] = fmaf(zi, wB.z, t[6]); t[7] = fmaf(zi, wB.w, t[7]);
        }
        #pragma unroll
        for (int q = 0; q < 8; ++q) {
            const float tq = fmaxf(t[q], 0.0f);
            const float* wr = w2s + (j0 + q) * HH;
            #pragma unroll
            for (int kc = 0; kc < 16; ++kc) {
                const float4 wv4 = *(const float4*)&wr[kc * 4];
                v[kc*4+0] = fmaf(tq, wv4.x, v[kc*4+0]);
                v[kc*4+1] = fmaf(tq, wv4.y, v[kc*4+1]);
                v[kc*4+2] = fmaf(tq, wv4.z, v[kc*4+2]);
                v[kc*4+3] = fmaf(tq, wv4.w, v[kc*4+3]);
            }
        }
    }
    #pragma unroll
    for (int k = 0; k < HH; ++k) v[k] = fmaxf(v[k], 0.0f);

    const int valid = min(64, NN - base);
    float s1 = 0.0f, s2 = 0.0f;
    #pragma unroll 1
    for (int cb = 0; cb < 8; ++cb) {
        const int r = lane & 7;
        if ((lane >> 3) == cb && cb * 8 + r < valid) {
            #pragma unroll
            for (int kc = 0; kc < 16; ++kc)
                *(float4*)&T[r * 68 + kc * 4] =
                    float4{v[kc*4], v[kc*4+1], v[kc*4+2], v[kc*4+3]};
        }
        wave_lds_sync();
        const int lim = min(max(valid - cb * 8, 0), 8);
        for (int e2 = 0; e2 < lim; ++e2) {
            const int nn2 = base + cb * 8 + e2;
            const float val = T[e2 * 68 + lane];
            agg[(size_t)nn2 * HH + lane] = val;
            s1 += val;
            s2 += val * val;
        }
        wave_lds_sync();
    }
    atomicAdd(&stats[lane], s1);
    atomicAdd(&stats[64 + lane], s2);
}

// ---------------------------------------------------------------------------
__global__ void bn_finalize(float* stats) {
    int j = threadIdx.x;
    if (j < HH) {
        float mu  = stats[j] * (1.0f / NN);
        float var = stats[64 + j] * (1.0f / NN) - mu * mu;
        stats[128 + j] = mu;
        stats[192 + j] = 1.0f / sqrtf(var + 1e-5f);
    }
}

// BN apply + segmented graph-pool accumulation (batch sorted).
#define CHUNK 32
__global__ void bn_apply(
    const float* __restrict__ v, const float* __restrict__ stats,
    const float* __restrict__ gamma, const float* __restrict__ beta,
    const int* __restrict__ batch,
    float* __restrict__ hout, float* __restrict__ pooled, int layer)
{
    const int lane = threadIdx.x & 63;
    const int wv   = (blockIdx.x * blockDim.x + threadIdx.x) >> 6;
    const int n0   = wv * CHUNK;
    if (n0 >= NN) return;
    const int n1 = min(n0 + CHUNK, NN);
    const float mu = stats[128 + lane], rs = stats[192 + lane];
    const float ga = gamma[lane],       be = beta[lane];
    float acc = 0.0f;
    int cur = batch[n0];
    for (int n = n0; n < n1; ++n) {
        const int b = batch[n];                       // uniform
        const float z = (v[(size_t)n * HH + lane] - mu) * rs * ga + be;
        hout[(size_t)n * HH + lane] = z;
        if (b != cur) {                               // uniform branch
            atomicAdd(&pooled[(size_t)cur * (NL * HH) + layer * HH + lane], acc);
            acc = 0.0f; cur = b;
        }
        acc += z;
    }
    atomicAdd(&pooled[(size_t)cur * (NL * HH) + layer * HH + lane], acc);
}

// ---------------------------------------------------------------------------
__global__ __launch_bounds__(256, 1) void graph_kernel(
    const float* __restrict__ pooled, const float* __restrict__ cnt,
    const float* __restrict__ fc0_w, const float* __restrict__ fc0_b,
    const float* __restrict__ wts, const int* __restrict__ sgb,
    float* __restrict__ s_acc)
{
    __shared__ float w[NL * HH * HH];   // 48KB
    for (int i = threadIdx.x; i < NL * HH * HH; i += blockDim.x) w[i] = fc0_w[i];
    __syncthreads();
    const int lane = threadIdx.x & 63;
    const int g = blockIdx.x * 4 + (threadIdx.x >> 6);
    if (g >= NG) return;
    const float inv = 1.0f / fmaxf(cnt[g], 1.0f);
    float acc = fc0_b[lane];
    #pragma unroll
    for (int c = 0; c < NL; ++c) {
        const float a = pooled[g * (NL * HH) + c * HH + lane] * inv;
        #pragma unroll
        for (int k = 0; k < HH; ++k)
            acc = fmaf(bcastf(a, k), w[(c * HH + k) * HH + lane], acc);
    }
    const float og = fmaxf(acc, 0.0f) * wts[g];
    atomicAdd(&s_acc[sgb[g] * HH + lane], og);
}

__global__ __launch_bounds__(256, 1) void final_kernel(
    const float* __restrict__ s_acc, const float* __restrict__ norm,
    const float* __restrict__ fc1_w, const float* __restrict__ fc1_b,
    const float* __restrict__ fc2_w, const float* __restrict__ fc2_b,
    const float* __restrict__ pw, const float* __restrict__ pb,
    float* __restrict__ out)
{
    const int lane = threadIdx.x & 63;
    const int s = blockIdx.x * 4 + (threadIdx.x >> 6);
    if (s >= NSG) return;
    const float xv = s_acc[s * HH + lane] / fmaxf(norm[s], 1e-12f);
    float u = fc1_b[lane];
    #pragma unroll
    for (int k = 0; k < HH; ++k) u = fmaf(bcastf(xv, k), fc1_w[k * HH + lane], u);
    u = fmaxf(u, 0.0f);
    float v = fc2_b[lane];
    #pragma unroll
    for (int k = 0; k < HH; ++k) v = fmaf(bcastf(u, k), fc2_w[k * HH + lane], v);
    v = fmaxf(v, 0.0f);
    float o = pb[lane & 31];
    #pragma unroll
    for (int k = 0; k < HH; ++k) o = fmaf(bcastf(v, k), pw[k * NOUT + (lane & 31)], o);
    if (lane < NOUT) out[s * NOUT + lane] = o;
}

// ---------------------------------------------------------------------------
extern "C" void kernel_launch(void* const* d_in, const int* in_sizes, int n_in,
                              void* d_out, int out_size, void* d_ws, size_t ws_size,
                              hipStream_t stream)
{
    const float* x        = (const float*)d_in[0];
    const int*   eidx     = (const int*)d_in[1];
    const float* eattr    = (const float*)d_in[2];
    const int*   batch    = (const int*)d_in[3];
    const float* weights  = (const float*)d_in[4];
    const int*   sgb      = (const int*)d_in[5];
    const float* be_w1    = (const float*)d_in[6];
    const float* be_b1    = (const float*)d_in[7];
    const float* be_w2    = (const float*)d_in[8];
    const float* be_b2    = (const float*)d_in[9];
    const float* mlp_w1   = (const float*)d_in[10];
    const float* mlp_b1   = (const float*)d_in[11];
    const float* mlp_w2   = (const float*)d_in[12];
    const float* mlp_b2   = (const float*)d_in[13];
    const float* eps      = (const float*)d_in[14];
    const float* bn_gamma = (const float*)d_in[15];
    const float* bn_beta  = (const float*)d_in[16];
    const float* fc0_w    = (const float*)d_in[17];
    const float* fc0_b    = (const float*)d_in[18];
    const float* fc1_w    = (const float*)d_in[19];
    const float* fc1_b    = (const float*)d_in[20];
    const float* fc2_w    = (const float*)d_in[21];
    const float* fc2_b    = (const float*)d_in[22];
    const float* pred_w   = (const float*)d_in[23];
    const float* pred_b   = (const float*)d_in[24];
    float* out = (float*)d_out;

    float* ws     = (float*)d_ws;
    float* h_buf  = ws;                               // NN*64
    float* agg    = ws + (size_t)NN * HH;             // NN*64 (also holds v)
    float* pooled = ws + (size_t)NN * HH * 2;         // NG*192
    float* cnt    = pooled + (size_t)NG * NL * HH;    // NG
    float* stats  = cnt + NG;                         // 256
    float* s_acc  = stats + 256;                      // NSG*64
    float* norm   = s_acc + (size_t)NSG * HH;         // NSG
    int*   ioff   = (int*)(norm + NSG);               // NN   (hist -> offsets -> cursors)
    int*   bsum   = ioff + NN;                        // 512
    int*   perm_s = bsum + 512;                       // NE
    int*   src_s  = perm_s + NE;                      // NE
    int*   dst_s  = src_s + NE;                       // NE

    size_t acc_floats = (size_t)NG * NL * HH + NG + 256 + (size_t)NSG * HH + NSG;
    hipMemsetAsync(pooled, 0, acc_floats * sizeof(float), stream);
    hipMemsetAsync(ioff, 0, NN * sizeof(int), stream);

    // ---- counting sort of edges by dst (once per call, reused by 3 layers)
    const int nb = (NN + 255) / 256;                  // 391 blocks
    hist_kernel<<<(NE + 255) / 256, 256, 0, stream>>>(eidx, ioff);
    scan1<<<nb, 256, 0, stream>>>(ioff, bsum);
    scan2<<<1, 512, 0, stream>>>(bsum, nb);
    scan3<<<nb, 256, 0, stream>>>(ioff, bsum);
    scatter_kernel<<<(NE + 255) / 256, 256, 0, stream>>>(eidx, ioff, perm_s, src_s, dst_s);

    cnt_kernel<<<(NN + 255) / 256, 256, 0, stream>>>(batch, cnt);
    norm_kernel<<<4, 256, 0, stream>>>(sgb, weights, norm);

    const float* hin = x;
    const int egroups = NE / 16;                      // 62500
    const int ewaves  = (egroups + GPW - 1) / GPW;    // 15625
    const int eblocks = (ewaves + 3) / 4;             // 3907
    const int node_tiles = (NN + 63) / 64;
    const int node_blocks = (node_tiles + 3) / 4;
    const int bn_waves  = (NN + CHUNK - 1) / CHUNK;
    const int bn_blocks = (bn_waves + 3) / 4;
    for (int l = 0; l < NL; ++l) {
        hipMemsetAsync(agg, 0, (size_t)NN * HH * sizeof(float), stream);
        hipMemsetAsync(stats, 0, 256 * sizeof(float), stream);
        edge_mfma<<<eblocks, 256, 0, stream>>>(
            hin, eattr, perm_s, src_s, dst_s,
            be_w1 + l * EF * HH, be_b1 + l * HH,
            be_w2 + l * HH * HH, be_b2 + l * HH, agg);
        node_fused<<<node_blocks, 256, 0, stream>>>(
            hin, agg,
            mlp_w1 + l * HH * HH, mlp_b1 + l * HH,
            mlp_w2 + l * HH * HH, mlp_b2 + l * HH,
            eps + l, stats);
        bn_finalize<<<1, 64, 0, stream>>>(stats);
        bn_apply<<<bn_blocks, 256, 0, stream>>>(
            agg, stats, bn_gamma + l * HH, bn_beta + l * HH,
            batch, h_buf, pooled, l);
        hin = h_buf;
    }

    graph_kernel<<<NG / 4, 256, 0, stream>>>(pooled, cnt, fc0_w, fc0_b,
                                             weights, sgb, s_acc);
    final_kernel<<<NSG / 4, 256, 0, stream>>>(s_acc, norm, fc1_w, fc1_b,
                                              fc2_w, fc2_b, pred_w, pred_b, out);
}